// Round 5
// baseline (93.106 us; speedup 1.0000x reference)
//
#include <hip/hip_runtime.h>
#include <math.h>

#define NN  62
#define BGR 512
#define FIN 128
#define HD  64
#define NC  3

typedef __attribute__((ext_vector_type(8))) short          bf16x8;
typedef __attribute__((ext_vector_type(4))) float          f32x4;
typedef __attribute__((ext_vector_type(4))) unsigned short us4;

static __device__ __forceinline__ unsigned short f2bf(float f) {
    union { float f; unsigned u; } v; v.f = f;
    unsigned u = v.u;
    return (unsigned short)((u + 0x7fffu + ((u >> 16) & 1u)) >> 16);   // RNE
}
static __device__ __forceinline__ float bf2f(unsigned short h) {
    union { unsigned u; float f; } v; v.u = ((unsigned)h) << 16;
    return v.f;
}

// v6: 2 graphs/block, 256 blocks x 512 threads. vs v5 (92.5 µs):
//  - Phase balance: waves 4-7's X f32->split-bf16 CONVERSION deferred into the
//    A-build slot (where they idled); raw X loads still issued at kernel entry
//    into registers for all waves (no added latency exposure).
//  - Barrier count 5 -> 4: A^2 gets its own LDS region (no overwrite of A, so
//    the "A-reads done" barrier disappears). LDS ~111 KB, still 1 block/CU.
//  - Pool: quad-butterfly (__shfl_xor 16/32) pre-reduces in-register; tail
//    reads 4 partials instead of 16. (FP association change only.)
// LDS map (ushort offsets in SH):
//  WHI  [0,8704) stride 136      | WLO  [8704,17408)
//  AHI  [17408,22016) stride 72  | ALO  [22016,26624)
//  A2HI [26624,31232) stride 72  | A2LO [31232,35840)
//  YT_A HI [35840,40448)         | LO [40448,45056)
//  YT_B HI [45056,49664)         | LO [49664,54272)
__global__ __launch_bounds__(512) void gcn_all(
    const float* __restrict__ x, const float* __restrict__ tril,
    const float* __restrict__ W1, const float* __restrict__ b1,
    const float* __restrict__ W2, const float* __restrict__ b2,
    float* __restrict__ out) {
    __shared__ unsigned short SH[54272];          // 106 KB
    __shared__ float TAIL[512 + 64 + 64];         // partial2(2x4x64), b1S(64), dinv(64)
    float* partial2 = TAIL;
    float* b1S      = TAIL + 512;
    float* dinvS    = TAIL + 576;

    const int t = threadIdx.x;
    const int gb = blockIdx.x;
    const int lane = t & 63, wv = t >> 6, quad = lane >> 4, l15 = lane & 15;
    const int w4 = wv & 3, gsel = wv >> 2;
    const int graph = 2 * gb + gsel;

    if (t < 16) *(float4*)&b1S[4 * t] = ((const float4*)b1)[t];

    // ---- X raw loads: issued at entry for ALL waves (latency hides under
    //      the staging phase); conversion deferred per wave-half. ----
    const int arow_i = 16 * w4 + l15;      // own A/X row
    float4 xr4[8];
    {
        if (arow_i < NN) {
            const float4* p4 = (const float4*)(x + (size_t)graph * NN * FIN
                                               + (size_t)arow_i * FIN + quad * 8);
#pragma unroll
            for (int c = 0; c < 4; ++c) { xr4[2*c] = p4[8*c]; xr4[2*c+1] = p4[8*c+1]; }
        } else {
            float4 zz = {0.f, 0.f, 0.f, 0.f};
#pragma unroll
            for (int c = 0; c < 8; ++c) xr4[c] = zz;
        }
    }
    bf16x8 xh[4], xl[4];
#define XCONV() { \
    _Pragma("unroll") \
    for (int c = 0; c < 4; ++c) { \
        float vv[8] = {xr4[2*c].x, xr4[2*c].y, xr4[2*c].z, xr4[2*c].w, \
                       xr4[2*c+1].x, xr4[2*c+1].y, xr4[2*c+1].z, xr4[2*c+1].w}; \
        _Pragma("unroll") \
        for (int k = 0; k < 8; ++k) { \
            unsigned short h = f2bf(vv[k]); \
            xh[c][k] = (short)h; \
            xl[c][k] = (short)f2bf(vv[k] - bf2f(h)); \
        } \
    } }

    const int jbase = 16 * quad;           // own A col-chunk (waves 0-3)
    float wreg[16];
    float dinv_r = 0.f;

    if (gsel == 1) {
        // ---- waves 4-7: stage W1 split (invariant; once per block) ----
        const float4* w14 = (const float4*)W1;
        for (int e = t - 256; e < 2048; e += 256) {
            int h = e >> 5, f4 = e & 31;
            float4 v = w14[e];
            us4 hh, ll;
            hh[0] = f2bf(v.x); ll[0] = f2bf(v.x - bf2f(hh[0]));
            hh[1] = f2bf(v.y); ll[1] = f2bf(v.y - bf2f(hh[1]));
            hh[2] = f2bf(v.z); ll[2] = f2bf(v.z - bf2f(hh[2]));
            hh[3] = f2bf(v.w); ll[3] = f2bf(v.w - bf2f(hh[3]));
            *(us4*)&SH[       h * 136 + f4 * 4] = hh;
            *(us4*)&SH[8704 + h * 136 + f4 * 4] = ll;
        }
    } else {
        // ---- waves 0-3: dinv (all 256 threads) + own X conversion ----
        float ps = 0.f;
#pragma unroll
        for (int jj = 0; jj < 16; ++jj) {
            int j = jbase + jj;
            float w = 0.f;
            if (arow_i < NN && j < NN) {
                int hi = arow_i > j ? arow_i : j;
                int lo = arow_i > j ? j : arow_i;
                w = tril[hi * (hi + 1) / 2 + lo];
            }
            wreg[jj] = w;
            ps += fabsf(w);
        }
        ps += __shfl_xor(ps, 16);
        ps += __shfl_xor(ps, 32);
        dinv_r = (ps > 0.f) ? (1.0f / sqrtf(ps)) : 0.f;   // 0 for rows >=62
        if (lane < 16) dinvS[16 * w4 + lane] = dinv_r;
        XCONV()
    }
    __syncthreads();      // (1) dinvS + W staged

    if (gsel == 0) {
        // ---- waves 0-3: A = D^-1/2 W D^-1/2 split-bf16 from registers ----
        const float di = dinv_r;
#pragma unroll
        for (int k = 0; k < 4; ++k) {
            float4 d4 = *(float4*)&dinvS[jbase + 4 * k];
            float dja[4] = {d4.x, d4.y, d4.z, d4.w};
            us4 hh, ll;
#pragma unroll
            for (int e = 0; e < 4; ++e) {
                float v = di * wreg[4 * k + e] * dja[e];
                hh[e] = f2bf(v);
                ll[e] = f2bf(v - bf2f(hh[e]));
            }
            *(us4*)&SH[17408 + arow_i * 72 + jbase + 4 * k] = hh;
            *(us4*)&SH[22016 + arow_i * 72 + jbase + 4 * k] = ll;
        }
    } else {
        // ---- waves 4-7: X conversion in the A-build bubble ----
        XCONV()
    }
#undef XCONV
    __syncthreads();      // (2) A staged

    // ---- A^2 = A @ A, 8-way split (wave -> NT tiles {2gsel, 2gsel+1}),
    //      3-term split (lo*lo dropped) ----
    f32x4 za0 = {0,0,0,0}, za1 = {0,0,0,0};
    {
        const int arow = 17408 + arow_i * 72 + quad * 8;
        const int nt0 = 2 * gsel;
#pragma unroll
        for (int c = 0; c < 2; ++c) {
            bf16x8 ahi = *(bf16x8*)&SH[arow + c * 32];
            bf16x8 alo = *(bf16x8*)&SH[4608 + arow + c * 32];
#define ATILE(ACC, NT) { \
            int bo = 17408 + (16 * (NT) + l15) * 72 + quad * 8 + c * 32; \
            bf16x8 bhi = *(bf16x8*)&SH[bo]; \
            bf16x8 blo = *(bf16x8*)&SH[4608 + bo]; \
            ACC = __builtin_amdgcn_mfma_f32_16x16x32_bf16(ahi, bhi, ACC, 0, 0, 0); \
            ACC = __builtin_amdgcn_mfma_f32_16x16x32_bf16(ahi, blo, ACC, 0, 0, 0); \
            ACC = __builtin_amdgcn_mfma_f32_16x16x32_bf16(alo, bhi, ACC, 0, 0, 0); }
            ATILE(za0, nt0) ATILE(za1, nt0 + 1)
#undef ATILE
        }
    }

    // ---- P1: Y = X @ W1^T (own graph), 3-term split ----
    f32x4 y0 = {0,0,0,0}, y1 = {0,0,0,0}, y2 = {0,0,0,0}, y3 = {0,0,0,0};
    {
#pragma unroll
        for (int c = 0; c < 4; ++c) {
            bf16x8 ahi = xh[c];
            bf16x8 alo = xl[c];
#define P1TILE(ACC, NT) { \
            int bo = (16 * (NT) + l15) * 136 + quad * 8 + c * 32; \
            bf16x8 bhi = *(bf16x8*)&SH[bo]; \
            bf16x8 blo = *(bf16x8*)&SH[8704 + bo]; \
            ACC = __builtin_amdgcn_mfma_f32_16x16x32_bf16(ahi, bhi, ACC, 0, 0, 0); \
            ACC = __builtin_amdgcn_mfma_f32_16x16x32_bf16(ahi, blo, ACC, 0, 0, 0); \
            ACC = __builtin_amdgcn_mfma_f32_16x16x32_bf16(alo, bhi, ACC, 0, 0, 0); }
            P1TILE(y0, 0) P1TILE(y1, 1) P1TILE(y2, 2) P1TILE(y3, 3)
#undef P1TILE
        }
    }

    // ---- write YT (own region) and A2 (own tiles; symmetric => transposed
    //      store == itself). A region is dead; no barrier needed before
    //      these writes (fresh regions). ----
    const int ytbase = 35840 + gsel * 9216;
    {
        const int mbase = 16 * w4 + quad * 4;
#define SPLITW(ACC, NT, HIOFF, LOOFF) { \
        int n = 16 * (NT) + l15; \
        us4 hh, ll; \
        hh[0] = f2bf(ACC[0]); ll[0] = f2bf(ACC[0] - bf2f(hh[0])); \
        hh[1] = f2bf(ACC[1]); ll[1] = f2bf(ACC[1] - bf2f(hh[1])); \
        hh[2] = f2bf(ACC[2]); ll[2] = f2bf(ACC[2] - bf2f(hh[2])); \
        hh[3] = f2bf(ACC[3]); ll[3] = f2bf(ACC[3] - bf2f(hh[3])); \
        *(us4*)&SH[(HIOFF) + n * 72 + mbase] = hh; \
        *(us4*)&SH[(LOOFF) + n * 72 + mbase] = ll; }
        SPLITW(y0, 0, ytbase, ytbase + 4608) SPLITW(y1, 1, ytbase, ytbase + 4608)
        SPLITW(y2, 2, ytbase, ytbase + 4608) SPLITW(y3, 3, ytbase, ytbase + 4608)
        SPLITW(za0, 2 * gsel,     26624, 31232)
        SPLITW(za1, 2 * gsel + 1, 26624, 31232)
#undef SPLITW
    }
    __syncthreads();      // (3) A2 + both YT staged

    // ---- P2: Z = A2 @ Y (own graph), 3-term split ----
    f32x4 z0 = {0,0,0,0}, z1 = {0,0,0,0}, z2 = {0,0,0,0}, z3 = {0,0,0,0};
    {
        const int arow = 26624 + arow_i * 72 + quad * 8;
#pragma unroll
        for (int c = 0; c < 2; ++c) {
            bf16x8 ahi = *(bf16x8*)&SH[arow + c * 32];
            bf16x8 alo = *(bf16x8*)&SH[4608 + arow + c * 32];
#define P2TILE(ACC, NT) { \
            int bo = ytbase + (16 * (NT) + l15) * 72 + quad * 8 + c * 32; \
            bf16x8 bhi = *(bf16x8*)&SH[bo]; \
            bf16x8 blo = *(bf16x8*)&SH[4608 + bo]; \
            ACC = __builtin_amdgcn_mfma_f32_16x16x32_bf16(ahi, bhi, ACC, 0, 0, 0); \
            ACC = __builtin_amdgcn_mfma_f32_16x16x32_bf16(ahi, blo, ACC, 0, 0, 0); \
            ACC = __builtin_amdgcn_mfma_f32_16x16x32_bf16(alo, bhi, ACC, 0, 0, 0); }
            P2TILE(z0, 0) P2TILE(z1, 1) P2TILE(z2, 2) P2TILE(z3, 3)
#undef P2TILE
        }
    }

    // ---- epilogue: +b1, relu, mask pad rows; quad-butterfly pool ----
    {
        const int mbase = 16 * w4 + quad * 4;
        float pv[4];
#define POOL(ACC, NT) { \
        int n = 16 * (NT) + l15; \
        float bn = b1S[n]; \
        float p = 0.f; \
        if (mbase + 0 < 62) p += fmaxf(ACC[0] + bn, 0.f); \
        if (mbase + 1 < 62) p += fmaxf(ACC[1] + bn, 0.f); \
        if (mbase + 2 < 62) p += fmaxf(ACC[2] + bn, 0.f); \
        if (mbase + 3 < 62) p += fmaxf(ACC[3] + bn, 0.f); \
        p += __shfl_xor(p, 16); \
        p += __shfl_xor(p, 32); \
        pv[NT] = p; }
        POOL(z0, 0) POOL(z1, 1) POOL(z2, 2) POOL(z3, 3)
#undef POOL
        // lane == 16*quad + l15; after butterfly each lane holds the
        // quad-summed pool for column n = 16*NT + l15; write NT == quad.
        float sel = (quad == 0) ? pv[0] : (quad == 1) ? pv[1]
                  : (quad == 2) ? pv[2] : pv[3];
        partial2[gsel * 256 + w4 * 64 + lane] = sel;
    }
    __syncthreads();      // (4) partials ready

    // ---- tails: wave 0 -> graph 2g, wave 4 -> graph 2g+1 ----
    int tg = -1, tt = 0;
    if (t < 64)                    { tg = 0; tt = t; }
    else if (t >= 256 && t < 320)  { tg = 1; tt = t - 256; }
    if (tg >= 0) {
        const float* part = partial2 + tg * 256;
        const int gr = 2 * gb + tg;
        float s = part[tt] + part[64 + tt] + part[128 + tt] + part[192 + tt];
        out[(size_t)gr * HD + tt] = s;
        float l0 = s * W2[tt];                // W2 rows: [c][h], 768 B, L2-hot
        float l1 = s * W2[64 + tt];
        float l2 = s * W2[128 + tt];
#pragma unroll
        for (int off = 32; off > 0; off >>= 1) {
            l0 += __shfl_down(l0, off);
            l1 += __shfl_down(l1, off);
            l2 += __shfl_down(l2, off);
        }
        if (tt == 0) {
            l0 += b2[0]; l1 += b2[1]; l2 += b2[2];
            float m = fmaxf(l0, fmaxf(l1, l2));
            float lse = m + logf(expf(l0 - m) + expf(l1 - m) + expf(l2 - m));
            float* lp = out + (size_t)BGR * HD + (size_t)gr * NC;
            lp[0] = l0 - lse; lp[1] = l1 - lse; lp[2] = l2 - lse;
        }
    }
}

extern "C" void kernel_launch(void* const* d_in, const int* in_sizes, int n_in,
                              void* d_out, int out_size, void* d_ws, size_t ws_size,
                              hipStream_t stream) {
    const float* x    = (const float*)d_in[0];
    const float* tril = (const float*)d_in[1];
    const float* W1   = (const float*)d_in[2];
    const float* b1   = (const float*)d_in[3];
    const float* W2   = (const float*)d_in[4];
    const float* b2   = (const float*)d_in[5];
    float* out = (float*)d_out;

    gcn_all<<<BGR / 2, 512, 0, stream>>>(x, tril, W1, b1, W2, b2, out);
}